// Round 16
// baseline (291.223 us; speedup 1.0000x reference)
//
#include <hip/hip_runtime.h>

// ---------------- problem constants ----------------
#define BROWS 262144
#define OUT_TASK_F32 8388608   // 262144*32 f32 per task; d_out = [T=3][B][32] f32

// ws layout (bytes)
#define WS_L1F 0          // 48 ntile * 4 kstep * 64 lane * 8 bf16 = 196608 B
#define WS_L2F 196608     // 19 ntile * 2 kstep * 64 lane * 8 bf16 = 38912 B
#define WS_B1  235520     // 768 f32 (layer-1 bias, padded cols -> 0)
#define WS_B2  238592     // 304 f32 (layer-2 bias: 8*32 expert + 3*16 gate-pad)

// LDS regions (bytes)  -- M=32 per iter as 2 subtiles of 16 rows
#define H1B 0             // h1 bf16 [2 sub][16][768], XOR-swz           49152
#define EOB 49152         // expert out f32 [2 sub][16][8 e][32 o], swz  32768
#define SGB 81920         // gate probs f32 [2 sub][16][3 t][8 e]         3072
#define LDS_TOTAL 84992   // x staging removed: per-wave register prefetch

typedef __attribute__((ext_vector_type(8))) short bf16x8;
typedef __attribute__((ext_vector_type(4))) float f32x4;
typedef __attribute__((ext_vector_type(2))) unsigned int u32x2;
typedef __attribute__((ext_vector_type(4))) unsigned int u32x4;

#define MFMA16(a, b, c) __builtin_amdgcn_mfma_f32_16x16x32_bf16((a), (b), (c), 0, 0, 0)

__device__ __forceinline__ unsigned short f2bf(float f) {
  unsigned int u = __float_as_uint(f);
  return (unsigned short)((u + 0x7FFFu + ((u >> 16) & 1u)) >> 16);  // RNE
}
__device__ __forceinline__ unsigned int cvtpk(float lo, float hi) {
  unsigned int r;
  asm("v_cvt_pk_bf16_f32 %0, %1, %2" : "=v"(r) : "v"(lo), "v"(hi));
  return r;
}

// ---------------- weight packing (unchanged; verified) ----------------
__global__ void pack_kernel(const float* __restrict__ We1, const float* __restrict__ be1,
                            const float* __restrict__ We2, const float* __restrict__ be2,
                            const float* __restrict__ Wg1, const float* __restrict__ bg1,
                            const float* __restrict__ Wg2, const float* __restrict__ bg2,
                            unsigned char* __restrict__ ws) {
  int idx = blockIdx.x * blockDim.x + threadIdx.x;
  unsigned short* L1F = (unsigned short*)(ws + WS_L1F);
  unsigned short* L2F = (unsigned short*)(ws + WS_L2F);
  float* B1 = (float*)(ws + WS_B1);
  float* B2 = (float*)(ws + WS_B2);
  if (idx < 98304) {
    int j = idx & 7, lane = (idx >> 3) & 63, ks = (idx >> 9) & 3, nt = idx >> 11;
    int k = ks * 32 + ((lane >> 4) << 3) + j;
    int n = nt * 16 + (lane & 15);
    float v = 0.f;
    if (n < 512)      v = We1[((n >> 6) * 128 + k) * 64 + (n & 63)];
    else if (n < 704) v = Wg1[(((n - 512) >> 6) * 128 + k) * 64 + ((n - 512) & 63)];
    L1F[idx] = f2bf(v);
  } else if (idx < 98304 + 19456) {
    int i2 = idx - 98304;
    int j = i2 & 7, lane = (i2 >> 3) & 63, ks = (i2 >> 9) & 1, nt = i2 >> 10;
    int k = ks * 32 + ((lane >> 4) << 3) + j;
    int n = nt * 16 + (lane & 15);
    float v = 0.f;
    if (n < 256) v = We2[((n >> 5) * 64 + k) * 32 + (n & 31)];
    else { int g = n - 256, t = g >> 4, eo = g & 15; if (eo < 8) v = Wg2[(t * 64 + k) * 8 + eo]; }
    L2F[i2] = f2bf(v);
  } else if (idx < 98304 + 19456 + 768) {
    int n = idx - (98304 + 19456);
    float v = 0.f;
    if (n < 512)      v = be1[n];
    else if (n < 704) v = bg1[n - 512];
    B1[n] = v;
  } else if (idx < 98304 + 19456 + 768 + 304) {
    int n = idx - (98304 + 19456 + 768);
    float v = 0.f;
    if (n < 256) v = be2[n];
    else { int g = n - 256, t = g >> 4, eo = g & 15; if (eo < 8) v = bg2[t * 8 + eo]; }
    B2[n] = v;
  }
}

// ---------------- fused MMoE: r15 + register-prefetched x (no LDS x staging) ----------------
// Each wave loads its OWN x fragments direct from global ONE ITERATION AHEAD into
// nx[2][8] float4 regs (r10's same-section global loads were latency-exposed; a full
// iteration ~7500 cyc covers them). Removes 96 b128 LDS ops/iter. LDS 101->85 KB.
__global__ __launch_bounds__(512, 2) void mmoe_kernel(const float* __restrict__ x,
                                                      const unsigned char* __restrict__ ws,
                                                      float* __restrict__ out) {
  __shared__ unsigned char lds[LDS_TOTAL];

  const int tid = threadIdx.x;
  const int l   = tid & 63;
  const int wid = tid >> 6;
  const int l15 = l & 15;
  const int lhi = l >> 4;
  const int swz = (l15 & 7) << 4;

  const bf16x8* L1F = (const bf16x8*)(ws + WS_L1F);
  const bf16x8* L2F = (const bf16x8*)(ws + WS_L2F);
  const float*  B1  = (const float*)(ws + WS_B1);
  const float*  B2  = (const float*)(ws + WS_B2);

  // ---- layer-1 ntile ownership: waves 0-5: 6 real tiles; waves 6,7: 4 real + 2 pad ----
  int ntb[6];
#pragma unroll
  for (int i = 0; i < 6; ++i) ntb[i] = wid * 6 + i;
  if (wid >= 6) {
    int b = wid - 6;
#pragma unroll
    for (int i = 0; i < 4; ++i) ntb[i] = 36 + b * 4 + i;
    ntb[4] = 44 + b * 2; ntb[5] = 45 + b * 2;
  }

  // ---- persistent weight fragments & biases ----
  bf16x8 w1f[6][4];
  f32x4 b1v[6];
#pragma unroll
  for (int i = 0; i < 6; ++i) {
#pragma unroll
    for (int ks = 0; ks < 4; ++ks) w1f[i][ks] = L1F[(ntb[i] * 4 + ks) * 64 + l];
    b1v[i] = *(const f32x4*)(B1 + ntb[i] * 16 + lhi * 4);
  }
  bf16x8 w2f[2][2];
  f32x4 b2v[2];
#pragma unroll
  for (int i = 0; i < 2; ++i) {
#pragma unroll
    for (int ks = 0; ks < 2; ++ks) w2f[i][ks] = L2F[((wid * 2 + i) * 2 + ks) * 64 + l];
    b2v[i] = *(const f32x4*)(B2 + wid * 32 + i * 16 + lhi * 4);
  }
  bf16x8 wgf[2];
  f32x4 bgv = (f32x4){0.f, 0.f, 0.f, 0.f};
  if (wid >= 5) {
    int t = wid - 5;
#pragma unroll
    for (int ks = 0; ks < 2; ++ks) wgf[ks] = L2F[((16 + t) * 2 + ks) * 64 + l];
    bgv = *(const f32x4*)(B2 + 256 + t * 16 + lhi * 4);
  }

  const int rowbase = blockIdx.x * 1024;   // 32 iters * 32 rows

  // ---- prologue: register-prefetch x fragments for iter 0 (both subtiles) ----
  float4 nx[2][8];
#pragma unroll
  for (int m = 0; m < 2; ++m) {
    const float* xp = x + (size_t)(rowbase + m * 16 + l15) * 128 + lhi * 8;
#pragma unroll
    for (int ks = 0; ks < 4; ++ks) {
      nx[m][2 * ks]     = *(const float4*)(xp + ks * 32);
      nx[m][2 * ks + 1] = *(const float4*)(xp + ks * 32 + 4);
    }
  }

  int dummy = 0; (void)dummy;
#pragma unroll 1
  for (int it = 0; it < 32; ++it) {
    const bool stage = (it + 1 < 32);

    // ======== section 1: combine(it-1) | L1 both subs (+ prefetch it+1) ========
    if (it > 0 && wid < 4) {  // combine + store for previous 32-row tile
      const int m = wid >> 1;              // subtile
      const int c = lhi + 4 * (wid & 1);   // 4-col chunk 0..7
      const unsigned char* sgp = lds + SGB + m * 1536 + l15 * 96;
      f32x4 g0a = *(const f32x4*)(sgp +  0), g0b = *(const f32x4*)(sgp + 16);
      f32x4 g1a = *(const f32x4*)(sgp + 32), g1b = *(const f32x4*)(sgp + 48);
      f32x4 g2a = *(const f32x4*)(sgp + 64), g2b = *(const f32x4*)(sgp + 80);
      f32x4 v0 = (f32x4){0.f,0.f,0.f,0.f}, v1 = v0, v2 = v0;
#pragma unroll
      for (int e = 0; e < 8; ++e) {
        f32x4 eo = *(const f32x4*)(lds + EOB + m * 16384 + l15 * 1024 +
                                   ((e * 128 + c * 16) ^ swz));
        float ga = (e < 4) ? g0a[e & 3] : g0b[e & 3];
        float gb = (e < 4) ? g1a[e & 3] : g1b[e & 3];
        float gc = (e < 4) ? g2a[e & 3] : g2b[e & 3];
        v0 += ga * eo; v1 += gb * eo; v2 += gc * eo;
      }
      size_t rowg = (size_t)(rowbase + (it - 1) * 32 + m * 16 + l15) * 32 + c * 4;
      *(float4*)(out + rowg)                    = (float4){v0[0], v0[1], v0[2], v0[3]};
      *(float4*)(out + OUT_TASK_F32 + rowg)     = (float4){v1[0], v1[1], v1[2], v1[3]};
      *(float4*)(out + 2 * OUT_TASK_F32 + rowg) = (float4){v2[0], v2[1], v2[2], v2[3]};
    }

#pragma unroll
    for (int m = 0; m < 2; ++m) {
      // convert prefetched regs -> bf16 fragments (frees nx[m])
      bf16x8 xa[4];
#pragma unroll
      for (int ks = 0; ks < 4; ++ks) {
        float4 a = nx[m][2 * ks], b = nx[m][2 * ks + 1];
        u32x4 u;
        u[0] = cvtpk(a.x, a.y); u[1] = cvtpk(a.z, a.w);
        u[2] = cvtpk(b.x, b.y); u[3] = cvtpk(b.z, b.w);
        xa[ks] = *(bf16x8*)&u;
      }
      // issue next iteration's fragment loads (land during section 2 + next combine)
      if (stage) {
        const float* xp = x + (size_t)(rowbase + (it + 1) * 32 + m * 16 + l15) * 128 + lhi * 8;
#pragma unroll
        for (int ks = 0; ks < 4; ++ks) {
          nx[m][2 * ks]     = *(const float4*)(xp + ks * 32);
          nx[m][2 * ks + 1] = *(const float4*)(xp + ks * 32 + 4);
        }
      }
      f32x4 acc[6];
#pragma unroll
      for (int i = 0; i < 6; ++i) acc[i] = b1v[i];
#pragma unroll
      for (int ks = 0; ks < 4; ++ks)
#pragma unroll
        for (int i = 0; i < 6; ++i)
          acc[i] = MFMA16(w1f[i][ks], xa[ks], acc[i]);
#pragma unroll
      for (int i = 0; i < 6; ++i) {
        u32x2 p;
        p[0] = cvtpk(fmaxf(acc[i][0], 0.f), fmaxf(acc[i][1], 0.f));
        p[1] = cvtpk(fmaxf(acc[i][2], 0.f), fmaxf(acc[i][3], 0.f));
        *(u32x2*)(lds + H1B + m * 24576 + l15 * 1536 + ((ntb[i] * 32 + lhi * 8) ^ swz)) = p;
      }
    }
    __syncthreads();  // bar1: h1 ready for both subs

    // ======== section 2: layer-2 + gate softmax (both subs) ========
#pragma unroll
    for (int m = 0; m < 2; ++m) {
      bf16x8 hb0 = *(const bf16x8*)(lds + H1B + m * 24576 + l15 * 1536 + ((wid * 128 + lhi * 16) ^ swz));
      bf16x8 hb1 = *(const bf16x8*)(lds + H1B + m * 24576 + l15 * 1536 + ((wid * 128 + 64 + lhi * 16) ^ swz));
      f32x4 a2[2] = {b2v[0], b2v[1]};
#pragma unroll
      for (int i = 0; i < 2; ++i) {
        a2[i] = MFMA16(w2f[i][0], hb0, a2[i]);
        a2[i] = MFMA16(w2f[i][1], hb1, a2[i]);
        f32x4 r;
        r[0] = fmaxf(a2[i][0], 0.f); r[1] = fmaxf(a2[i][1], 0.f);
        r[2] = fmaxf(a2[i][2], 0.f); r[3] = fmaxf(a2[i][3], 0.f);
        *(f32x4*)(lds + EOB + m * 16384 + l15 * 1024 + ((wid * 128 + i * 64 + lhi * 16) ^ swz)) = r;
      }

      if (wid >= 5) {  // gate for task wid-5, in-register softmax
        int t = wid - 5;
        bf16x8 gb0 = *(const bf16x8*)(lds + H1B + m * 24576 + l15 * 1536 + ((1024 + t * 128 + lhi * 16) ^ swz));
        bf16x8 gb1 = *(const bf16x8*)(lds + H1B + m * 24576 + l15 * 1536 + ((1024 + t * 128 + 64 + lhi * 16) ^ swz));
        f32x4 ag = bgv;
        ag = MFMA16(wgf[0], gb0, ag);
        ag = MFMA16(wgf[1], gb1, ag);
        float s0 = ag[0], s1 = ag[1], s2 = ag[2], s3 = ag[3];
        float o0 = __shfl_xor(s0, 16), o1 = __shfl_xor(s1, 16);
        float o2 = __shfl_xor(s2, 16), o3 = __shfl_xor(s3, 16);
        float mx = fmaxf(fmaxf(fmaxf(s0, s1), fmaxf(s2, s3)),
                         fmaxf(fmaxf(o0, o1), fmaxf(o2, o3)));
        float q0 = __expf(s0 - mx), q1 = __expf(s1 - mx), q2 = __expf(s2 - mx), q3 = __expf(s3 - mx);
        float ps = q0 + q1 + q2 + q3;
        float inv = 1.f / (ps + __shfl_xor(ps, 16));
        if (lhi < 2)
          *(f32x4*)(lds + SGB + m * 1536 + l15 * 96 + t * 32 + lhi * 16) =
              (f32x4){q0 * inv, q1 * inv, q2 * inv, q3 * inv};
      }
    }
    __syncthreads();  // bar2: EO/SG ready
  }

  // ---- epilogue: combine for the last tile ----
  if (wid < 4) {
    const int m = wid >> 1;
    const int c = lhi + 4 * (wid & 1);
    const unsigned char* sgp = lds + SGB + m * 1536 + l15 * 96;
    f32x4 g0a = *(const f32x4*)(sgp +  0), g0b = *(const f32x4*)(sgp + 16);
    f32x4 g1a = *(const f32x4*)(sgp + 32), g1b = *(const f32x4*)(sgp + 48);
    f32x4 g2a = *(const f32x4*)(sgp + 64), g2b = *(const f32x4*)(sgp + 80);
    f32x4 v0 = (f32x4){0.f,0.f,0.f,0.f}, v1 = v0, v2 = v0;
#pragma unroll
    for (int e = 0; e < 8; ++e) {
      f32x4 eo = *(const f32x4*)(lds + EOB + m * 16384 + l15 * 1024 +
                                 ((e * 128 + c * 16) ^ swz));
      float ga = (e < 4) ? g0a[e & 3] : g0b[e & 3];
      float gb = (e < 4) ? g1a[e & 3] : g1b[e & 3];
      float gc = (e < 4) ? g2a[e & 3] : g2b[e & 3];
      v0 += ga * eo; v1 += gb * eo; v2 += gc * eo;
    }
    size_t rowg = (size_t)(rowbase + 31 * 32 + m * 16 + l15) * 32 + c * 4;
    *(float4*)(out + rowg)                    = (float4){v0[0], v0[1], v0[2], v0[3]};
    *(float4*)(out + OUT_TASK_F32 + rowg)     = (float4){v1[0], v1[1], v1[2], v1[3]};
    *(float4*)(out + 2 * OUT_TASK_F32 + rowg) = (float4){v2[0], v2[1], v2[2], v2[3]};
  }
}

extern "C" void kernel_launch(void* const* d_in, const int* in_sizes, int n_in,
                              void* d_out, int out_size, void* d_ws, size_t ws_size,
                              hipStream_t stream) {
  const float* x   = (const float*)d_in[0];
  const float* We1 = (const float*)d_in[1];
  const float* be1 = (const float*)d_in[2];
  const float* We2 = (const float*)d_in[3];
  const float* be2 = (const float*)d_in[4];
  const float* Wg1 = (const float*)d_in[5];
  const float* bg1 = (const float*)d_in[6];
  const float* Wg2 = (const float*)d_in[7];
  const float* bg2 = (const float*)d_in[8];
  unsigned char* ws = (unsigned char*)d_ws;
  float* out = (float*)d_out;

  pack_kernel<<<465, 256, 0, stream>>>(We1, be1, We2, be2, Wg1, bg1, Wg2, bg2, ws);
  mmoe_kernel<<<256, 512, 0, stream>>>(x, ws, out);
}

// Round 17
// 89.812 us; speedup vs baseline: 3.2426x; 3.2426x over previous
//
#include <hip/hip_runtime.h>

// ---------------- problem constants ----------------
#define BROWS 262144
#define OUT_TASK_F32 8388608   // 262144*32 f32 per task; d_out = [T=3][B][32] f32

// ws layout (bytes)
#define WS_L1F 0          // 48 ntile * 4 kstep * 64 lane * 8 bf16 = 196608 B
#define WS_L2F 196608     // 19 ntile * 2 kstep * 64 lane * 8 bf16 = 38912 B
#define WS_B1  235520     // 768 f32 (layer-1 bias, padded cols -> 0)
#define WS_B2  238592     // 304 f32 (layer-2 bias: 8*32 expert + 3*16 gate-pad)

// LDS regions (bytes)  -- M=32 per iter as 2 subtiles of 16 rows
// EO/SG double-buffered on ITER PARITY so combine(it-1) can run in section 2
// concurrently with L2/gates(it).
#define H1B 0             // h1 bf16 [2 sub][16][768], XOR-swz                49152
#define EOB 49152         // expert out f32 [2 par][2 sub][16][8e][32o], swz  65536
#define SGB 114688        // gate probs f32 [2 par][2 sub][16][112B row]       7168
#define XSB 121856        // x bf16 [2 buf][2 sub][16][128]                   16384
#define LDS_TOTAL 138240

typedef __attribute__((ext_vector_type(8))) short bf16x8;
typedef __attribute__((ext_vector_type(4))) float f32x4;
typedef __attribute__((ext_vector_type(2))) unsigned int u32x2;
typedef __attribute__((ext_vector_type(4))) unsigned int u32x4;

#define MFMA16(a, b, c) __builtin_amdgcn_mfma_f32_16x16x32_bf16((a), (b), (c), 0, 0, 0)

__device__ __forceinline__ unsigned short f2bf(float f) {
  unsigned int u = __float_as_uint(f);
  return (unsigned short)((u + 0x7FFFu + ((u >> 16) & 1u)) >> 16);  // RNE
}
__device__ __forceinline__ unsigned int cvtpk(float lo, float hi) {
  unsigned int r;
  asm("v_cvt_pk_bf16_f32 %0, %1, %2" : "=v"(r) : "v"(lo), "v"(hi));
  return r;
}

// ---------------- weight packing (unchanged; verified) ----------------
__global__ void pack_kernel(const float* __restrict__ We1, const float* __restrict__ be1,
                            const float* __restrict__ We2, const float* __restrict__ be2,
                            const float* __restrict__ Wg1, const float* __restrict__ bg1,
                            const float* __restrict__ Wg2, const float* __restrict__ bg2,
                            unsigned char* __restrict__ ws) {
  int idx = blockIdx.x * blockDim.x + threadIdx.x;
  unsigned short* L1F = (unsigned short*)(ws + WS_L1F);
  unsigned short* L2F = (unsigned short*)(ws + WS_L2F);
  float* B1 = (float*)(ws + WS_B1);
  float* B2 = (float*)(ws + WS_B2);
  if (idx < 98304) {
    int j = idx & 7, lane = (idx >> 3) & 63, ks = (idx >> 9) & 3, nt = idx >> 11;
    int k = ks * 32 + ((lane >> 4) << 3) + j;
    int n = nt * 16 + (lane & 15);
    float v = 0.f;
    if (n < 512)      v = We1[((n >> 6) * 128 + k) * 64 + (n & 63)];
    else if (n < 704) v = Wg1[(((n - 512) >> 6) * 128 + k) * 64 + ((n - 512) & 63)];
    L1F[idx] = f2bf(v);
  } else if (idx < 98304 + 19456) {
    int i2 = idx - 98304;
    int j = i2 & 7, lane = (i2 >> 3) & 63, ks = (i2 >> 9) & 1, nt = i2 >> 10;
    int k = ks * 32 + ((lane >> 4) << 3) + j;
    int n = nt * 16 + (lane & 15);
    float v = 0.f;
    if (n < 256) v = We2[((n >> 5) * 64 + k) * 32 + (n & 31)];
    else { int g = n - 256, t = g >> 4, eo = g & 15; if (eo < 8) v = Wg2[(t * 64 + k) * 8 + eo]; }
    L2F[i2] = f2bf(v);
  } else if (idx < 98304 + 19456 + 768) {
    int n = idx - (98304 + 19456);
    float v = 0.f;
    if (n < 512)      v = be1[n];
    else if (n < 704) v = bg1[n - 512];
    B1[n] = v;
  } else if (idx < 98304 + 19456 + 768 + 304) {
    int n = idx - (98304 + 19456 + 768);
    float v = 0.f;
    if (n < 256) v = be2[n];
    else { int g = n - 256, t = g >> 4, eo = g & 15; if (eo < 8) v = bg2[t * 8 + eo]; }
    B2[n] = v;
  }
}

// ---------------- fused MMoE: r15 + combine moved to section 2 + SG de-conflict ----------------
// 8 waves, M=32/iter (2 subtiles), 2 barriers/iter, 256 blocks, LDS x staging.
// sec1: stage-issue x(it+1) | L1 both subs (all waves).
// sec2: L2 (all waves) | gates (waves 5-7) | combine(it-1) (waves 0-3, reads parity^1)
//       | stage-write x(it+1).
// SG rows padded to 112 B (28 dwords; 8 distinct bank starts -> 2-way = free).
__global__ __launch_bounds__(512, 2) void mmoe_kernel(const float* __restrict__ x,
                                                      const unsigned char* __restrict__ ws,
                                                      float* __restrict__ out) {
  __shared__ unsigned char lds[LDS_TOTAL];

  const int tid = threadIdx.x;
  const int l   = tid & 63;
  const int wid = tid >> 6;
  const int l15 = l & 15;
  const int lhi = l >> 4;
  const int swz = (l15 & 7) << 4;

  const bf16x8* L1F = (const bf16x8*)(ws + WS_L1F);
  const bf16x8* L2F = (const bf16x8*)(ws + WS_L2F);
  const float*  B1  = (const float*)(ws + WS_B1);
  const float*  B2  = (const float*)(ws + WS_B2);

  // ---- layer-1 ntile ownership: waves 0-5: 6 real tiles; waves 6,7: 4 real + 2 pad ----
  int ntb[6];
#pragma unroll
  for (int i = 0; i < 6; ++i) ntb[i] = wid * 6 + i;
  if (wid >= 6) {
    int b = wid - 6;
#pragma unroll
    for (int i = 0; i < 4; ++i) ntb[i] = 36 + b * 4 + i;
    ntb[4] = 44 + b * 2; ntb[5] = 45 + b * 2;
  }

  // ---- persistent weight fragments & biases ----
  bf16x8 w1f[6][4];
  f32x4 b1v[6];
#pragma unroll
  for (int i = 0; i < 6; ++i) {
#pragma unroll
    for (int ks = 0; ks < 4; ++ks) w1f[i][ks] = L1F[(ntb[i] * 4 + ks) * 64 + l];
    b1v[i] = *(const f32x4*)(B1 + ntb[i] * 16 + lhi * 4);
  }
  bf16x8 w2f[2][2];
  f32x4 b2v[2];
#pragma unroll
  for (int i = 0; i < 2; ++i) {
#pragma unroll
    for (int ks = 0; ks < 2; ++ks) w2f[i][ks] = L2F[((wid * 2 + i) * 2 + ks) * 64 + l];
    b2v[i] = *(const f32x4*)(B2 + wid * 32 + i * 16 + lhi * 4);
  }
  bf16x8 wgf[2];
  f32x4 bgv = (f32x4){0.f, 0.f, 0.f, 0.f};
  if (wid >= 5) {
    int t = wid - 5;
#pragma unroll
    for (int ks = 0; ks < 2; ++ks) wgf[ks] = L2F[((16 + t) * 2 + ks) * 64 + l];
    bgv = *(const f32x4*)(B2 + 256 + t * 16 + lhi * 4);
  }

  // ---- x staging mapping: thread -> (row 0..31, 8-float col group) ----
  const int r32 = tid >> 4;
  const int c8  = (tid & 15) * 8;
  const int sboff = (r32 >> 4) * 4096 + (r32 & 15) * 256 + (((tid & 15) * 16) ^ ((r32 & 7) << 4));
  const int rowbase = blockIdx.x * 1024;   // 32 iters * 32 rows

  {  // prologue: stage tile 0 into buf 0
    const float* xp = x + (size_t)(rowbase + r32) * 128 + c8;
    float4 a = *(const float4*)xp, b = *(const float4*)(xp + 4);
    u32x4 p; p[0] = cvtpk(a.x, a.y); p[1] = cvtpk(a.z, a.w);
    p[2] = cvtpk(b.x, b.y); p[3] = cvtpk(b.z, b.w);
    *(u32x4*)(lds + XSB + sboff) = p;
  }
  __syncthreads();

  int cur = 0;
#pragma unroll 1
  for (int it = 0; it < 32; ++it) {
    const int par = it & 1;
    const bool stage = (it + 1 < 32);

    // ======== section 1: stage-issue(it+1) | layer-1 both subs ========
    float4 sa, sb;
    if (stage) {
      const float* xp = x + (size_t)(rowbase + (it + 1) * 32 + r32) * 128 + c8;
      sa = *(const float4*)xp; sb = *(const float4*)(xp + 4);
    }

#pragma unroll
    for (int m = 0; m < 2; ++m) {
      bf16x8 xa[4];
#pragma unroll
      for (int ks = 0; ks < 4; ++ks)
        xa[ks] = *(const bf16x8*)(lds + XSB + cur * 8192 + m * 4096 + l15 * 256 +
                                  ((ks * 64 + lhi * 16) ^ swz));
      f32x4 acc[6];
#pragma unroll
      for (int i = 0; i < 6; ++i) acc[i] = b1v[i];
#pragma unroll
      for (int ks = 0; ks < 4; ++ks)
#pragma unroll
        for (int i = 0; i < 6; ++i)
          acc[i] = MFMA16(w1f[i][ks], xa[ks], acc[i]);
#pragma unroll
      for (int i = 0; i < 6; ++i) {
        u32x2 p;
        p[0] = cvtpk(fmaxf(acc[i][0], 0.f), fmaxf(acc[i][1], 0.f));
        p[1] = cvtpk(fmaxf(acc[i][2], 0.f), fmaxf(acc[i][3], 0.f));
        *(u32x2*)(lds + H1B + m * 24576 + l15 * 1536 + ((ntb[i] * 32 + lhi * 8) ^ swz)) = p;
      }
    }
    __syncthreads();  // bar1: h1 ready for both subs

    // ======== section 2: L2 | gates (w5-7) | combine(it-1) (w0-3) | stage-write ========
#pragma unroll
    for (int m = 0; m < 2; ++m) {
      bf16x8 hb0 = *(const bf16x8*)(lds + H1B + m * 24576 + l15 * 1536 + ((wid * 128 + lhi * 16) ^ swz));
      bf16x8 hb1 = *(const bf16x8*)(lds + H1B + m * 24576 + l15 * 1536 + ((wid * 128 + 64 + lhi * 16) ^ swz));
      f32x4 a2[2] = {b2v[0], b2v[1]};
#pragma unroll
      for (int i = 0; i < 2; ++i) {
        a2[i] = MFMA16(w2f[i][0], hb0, a2[i]);
        a2[i] = MFMA16(w2f[i][1], hb1, a2[i]);
        f32x4 r;
        r[0] = fmaxf(a2[i][0], 0.f); r[1] = fmaxf(a2[i][1], 0.f);
        r[2] = fmaxf(a2[i][2], 0.f); r[3] = fmaxf(a2[i][3], 0.f);
        *(f32x4*)(lds + EOB + par * 32768 + m * 16384 + l15 * 1024 +
                  ((wid * 128 + i * 64 + lhi * 16) ^ swz)) = r;
      }

      if (wid >= 5) {  // gate for task wid-5, in-register softmax
        int t = wid - 5;
        bf16x8 gb0 = *(const bf16x8*)(lds + H1B + m * 24576 + l15 * 1536 + ((1024 + t * 128 + lhi * 16) ^ swz));
        bf16x8 gb1 = *(const bf16x8*)(lds + H1B + m * 24576 + l15 * 1536 + ((1024 + t * 128 + 64 + lhi * 16) ^ swz));
        f32x4 ag = bgv;
        ag = MFMA16(wgf[0], gb0, ag);
        ag = MFMA16(wgf[1], gb1, ag);
        float s0 = ag[0], s1 = ag[1], s2 = ag[2], s3 = ag[3];
        float o0 = __shfl_xor(s0, 16), o1 = __shfl_xor(s1, 16);
        float o2 = __shfl_xor(s2, 16), o3 = __shfl_xor(s3, 16);
        float mx = fmaxf(fmaxf(fmaxf(s0, s1), fmaxf(s2, s3)),
                         fmaxf(fmaxf(o0, o1), fmaxf(o2, o3)));
        float q0 = __expf(s0 - mx), q1 = __expf(s1 - mx), q2 = __expf(s2 - mx), q3 = __expf(s3 - mx);
        float ps = q0 + q1 + q2 + q3;
        float inv = 1.f / (ps + __shfl_xor(ps, 16));
        if (lhi < 2)
          *(f32x4*)(lds + SGB + par * 3584 + m * 1792 + l15 * 112 + t * 32 + lhi * 16) =
              (f32x4){q0 * inv, q1 * inv, q2 * inv, q3 * inv};
      }
    }

    if (it > 0 && wid < 4) {  // combine + store for tile it-1 (parity^1 buffers)
      const int m = wid >> 1;              // subtile
      const int c = lhi + 4 * (wid & 1);   // 4-col chunk 0..7
      const unsigned char* sgp = lds + SGB + (par ^ 1) * 3584 + m * 1792 + l15 * 112;
      f32x4 g0a = *(const f32x4*)(sgp +  0), g0b = *(const f32x4*)(sgp + 16);
      f32x4 g1a = *(const f32x4*)(sgp + 32), g1b = *(const f32x4*)(sgp + 48);
      f32x4 g2a = *(const f32x4*)(sgp + 64), g2b = *(const f32x4*)(sgp + 80);
      f32x4 v0 = (f32x4){0.f,0.f,0.f,0.f}, v1 = v0, v2 = v0;
#pragma unroll
      for (int e = 0; e < 8; ++e) {
        f32x4 eo = *(const f32x4*)(lds + EOB + (par ^ 1) * 32768 + m * 16384 + l15 * 1024 +
                                   ((e * 128 + c * 16) ^ swz));
        float ga = (e < 4) ? g0a[e & 3] : g0b[e & 3];
        float gb = (e < 4) ? g1a[e & 3] : g1b[e & 3];
        float gc = (e < 4) ? g2a[e & 3] : g2b[e & 3];
        v0 += ga * eo; v1 += gb * eo; v2 += gc * eo;
      }
      size_t rowg = (size_t)(rowbase + (it - 1) * 32 + m * 16 + l15) * 32 + c * 4;
      *(float4*)(out + rowg)                    = (float4){v0[0], v0[1], v0[2], v0[3]};
      *(float4*)(out + OUT_TASK_F32 + rowg)     = (float4){v1[0], v1[1], v1[2], v1[3]};
      *(float4*)(out + 2 * OUT_TASK_F32 + rowg) = (float4){v2[0], v2[1], v2[2], v2[3]};
    }

    if (stage) {
      u32x4 p; p[0] = cvtpk(sa.x, sa.y); p[1] = cvtpk(sa.z, sa.w);
      p[2] = cvtpk(sb.x, sb.y); p[3] = cvtpk(sb.z, sb.w);
      *(u32x4*)(lds + XSB + (cur ^ 1) * 8192 + sboff) = p;
    }
    __syncthreads();  // bar2: EO/SG(par) ready, x(it+1) staged
    cur ^= 1;
  }

  // ---- epilogue: combine for the last tile (it=31 -> parity 1) ----
  if (wid < 4) {
    const int m = wid >> 1;
    const int c = lhi + 4 * (wid & 1);
    const unsigned char* sgp = lds + SGB + 1 * 3584 + m * 1792 + l15 * 112;
    f32x4 g0a = *(const f32x4*)(sgp +  0), g0b = *(const f32x4*)(sgp + 16);
    f32x4 g1a = *(const f32x4*)(sgp + 32), g1b = *(const f32x4*)(sgp + 48);
    f32x4 g2a = *(const f32x4*)(sgp + 64), g2b = *(const f32x4*)(sgp + 80);
    f32x4 v0 = (f32x4){0.f,0.f,0.f,0.f}, v1 = v0, v2 = v0;
#pragma unroll
    for (int e = 0; e < 8; ++e) {
      f32x4 eo = *(const f32x4*)(lds + EOB + 1 * 32768 + m * 16384 + l15 * 1024 +
                                 ((e * 128 + c * 16) ^ swz));
      float ga = (e < 4) ? g0a[e & 3] : g0b[e & 3];
      float gb = (e < 4) ? g1a[e & 3] : g1b[e & 3];
      float gc = (e < 4) ? g2a[e & 3] : g2b[e & 3];
      v0 += ga * eo; v1 += gb * eo; v2 += gc * eo;
    }
    size_t rowg = (size_t)(rowbase + 31 * 32 + m * 16 + l15) * 32 + c * 4;
    *(float4*)(out + rowg)                    = (float4){v0[0], v0[1], v0[2], v0[3]};
    *(float4*)(out + OUT_TASK_F32 + rowg)     = (float4){v1[0], v1[1], v1[2], v1[3]};
    *(float4*)(out + 2 * OUT_TASK_F32 + rowg) = (float4){v2[0], v2[1], v2[2], v2[3]};
  }
}

extern "C" void kernel_launch(void* const* d_in, const int* in_sizes, int n_in,
                              void* d_out, int out_size, void* d_ws, size_t ws_size,
                              hipStream_t stream) {
  const float* x   = (const float*)d_in[0];
  const float* We1 = (const float*)d_in[1];
  const float* be1 = (const float*)d_in[2];
  const float* We2 = (const float*)d_in[3];
  const float* be2 = (const float*)d_in[4];
  const float* Wg1 = (const float*)d_in[5];
  const float* bg1 = (const float*)d_in[6];
  const float* Wg2 = (const float*)d_in[7];
  const float* bg2 = (const float*)d_in[8];
  unsigned char* ws = (unsigned char*)d_ws;
  float* out = (float*)d_out;

  pack_kernel<<<465, 256, 0, stream>>>(We1, be1, We2, be2, Wg1, bg1, Wg2, bg2, ws);
  mmoe_kernel<<<256, 512, 0, stream>>>(x, ws, out);
}

// Round 18
// 88.850 us; speedup vs baseline: 3.2777x; 1.0108x over previous
//
#include <hip/hip_runtime.h>

// ---------------- problem constants ----------------
#define BROWS 262144
#define OUT_TASK_F32 8388608   // 262144*32 f32 per task; d_out = [T=3][B][32] f32

// ws layout (bytes)
#define WS_L1F 0          // 48 ntile * 4 kstep * 64 lane * 8 bf16 = 196608 B
#define WS_L2F 196608     // 19 ntile * 2 kstep * 64 lane * 8 bf16 = 38912 B
#define WS_B1  235520     // 768 f32 (layer-1 bias, padded cols -> 0)
#define WS_B2  238592     // 304 f32 (layer-2 bias: 8*32 expert + 3*16 gate-pad)

// LDS regions (bytes)  -- M=32 per iter as 2 subtiles of 16 rows
// EO/SG double-buffered on ITER PARITY (combine runs in sec2 on parity^1).
// EO now packed BF16: [2 par][2 sub][16 rows][8e*32o bf16 = 512 B], XOR-swz.
#define H1B 0             // h1 bf16 [2 sub][16][768], XOR-swz                49152
#define EOB 49152         // expert out bf16 [2 par][2 sub][16][512B]         32768
#define SGB 81920         // gate probs f32 [2 par][2 sub][16][112B row]       7168
#define XSB 89088         // x bf16 [2 buf][2 sub][16][128]                   16384
#define LDS_TOTAL 105472

typedef __attribute__((ext_vector_type(8))) short bf16x8;
typedef __attribute__((ext_vector_type(4))) float f32x4;
typedef __attribute__((ext_vector_type(2))) unsigned int u32x2;
typedef __attribute__((ext_vector_type(4))) unsigned int u32x4;

#define MFMA16(a, b, c) __builtin_amdgcn_mfma_f32_16x16x32_bf16((a), (b), (c), 0, 0, 0)

__device__ __forceinline__ unsigned short f2bf(float f) {
  unsigned int u = __float_as_uint(f);
  return (unsigned short)((u + 0x7FFFu + ((u >> 16) & 1u)) >> 16);  // RNE
}
__device__ __forceinline__ unsigned int cvtpk(float lo, float hi) {
  unsigned int r;
  asm("v_cvt_pk_bf16_f32 %0, %1, %2" : "=v"(r) : "v"(lo), "v"(hi));
  return r;
}

// ---------------- weight packing (unchanged; verified) ----------------
__global__ void pack_kernel(const float* __restrict__ We1, const float* __restrict__ be1,
                            const float* __restrict__ We2, const float* __restrict__ be2,
                            const float* __restrict__ Wg1, const float* __restrict__ bg1,
                            const float* __restrict__ Wg2, const float* __restrict__ bg2,
                            unsigned char* __restrict__ ws) {
  int idx = blockIdx.x * blockDim.x + threadIdx.x;
  unsigned short* L1F = (unsigned short*)(ws + WS_L1F);
  unsigned short* L2F = (unsigned short*)(ws + WS_L2F);
  float* B1 = (float*)(ws + WS_B1);
  float* B2 = (float*)(ws + WS_B2);
  if (idx < 98304) {
    int j = idx & 7, lane = (idx >> 3) & 63, ks = (idx >> 9) & 3, nt = idx >> 11;
    int k = ks * 32 + ((lane >> 4) << 3) + j;
    int n = nt * 16 + (lane & 15);
    float v = 0.f;
    if (n < 512)      v = We1[((n >> 6) * 128 + k) * 64 + (n & 63)];
    else if (n < 704) v = Wg1[(((n - 512) >> 6) * 128 + k) * 64 + ((n - 512) & 63)];
    L1F[idx] = f2bf(v);
  } else if (idx < 98304 + 19456) {
    int i2 = idx - 98304;
    int j = i2 & 7, lane = (i2 >> 3) & 63, ks = (i2 >> 9) & 1, nt = i2 >> 10;
    int k = ks * 32 + ((lane >> 4) << 3) + j;
    int n = nt * 16 + (lane & 15);
    float v = 0.f;
    if (n < 256) v = We2[((n >> 5) * 64 + k) * 32 + (n & 31)];
    else { int g = n - 256, t = g >> 4, eo = g & 15; if (eo < 8) v = Wg2[(t * 64 + k) * 8 + eo]; }
    L2F[i2] = f2bf(v);
  } else if (idx < 98304 + 19456 + 768) {
    int n = idx - (98304 + 19456);
    float v = 0.f;
    if (n < 512)      v = be1[n];
    else if (n < 704) v = bg1[n - 512];
    B1[n] = v;
  } else if (idx < 98304 + 19456 + 768 + 304) {
    int n = idx - (98304 + 19456 + 768);
    float v = 0.f;
    if (n < 256) v = be2[n];
    else { int g = n - 256, t = g >> 4, eo = g & 15; if (eo < 8) v = bg2[t * 8 + eo]; }
    B2[n] = v;
  }
}

// ---------------- fused MMoE: r17 + bf16-packed EO (halved EO LDS traffic) ----------------
// 8 waves, M=32/iter (2 subtiles), 2 barriers/iter, 256 blocks, LDS x staging.
// sec1: stage-issue x(it+1) | L1 both subs (all waves).
// sec2: L2 (all waves, EO->bf16 LDS) | gates (waves 5-7) | combine(it-1) (waves 0-3,
//       parity^1, bf16 unpack via shift/mask) | stage-write x(it+1).
__global__ __launch_bounds__(512, 2) void mmoe_kernel(const float* __restrict__ x,
                                                      const unsigned char* __restrict__ ws,
                                                      float* __restrict__ out) {
  __shared__ unsigned char lds[LDS_TOTAL];

  const int tid = threadIdx.x;
  const int l   = tid & 63;
  const int wid = tid >> 6;
  const int l15 = l & 15;
  const int lhi = l >> 4;
  const int swz = (l15 & 7) << 4;

  const bf16x8* L1F = (const bf16x8*)(ws + WS_L1F);
  const bf16x8* L2F = (const bf16x8*)(ws + WS_L2F);
  const float*  B1  = (const float*)(ws + WS_B1);
  const float*  B2  = (const float*)(ws + WS_B2);

  // ---- layer-1 ntile ownership: waves 0-5: 6 real tiles; waves 6,7: 4 real + 2 pad ----
  int ntb[6];
#pragma unroll
  for (int i = 0; i < 6; ++i) ntb[i] = wid * 6 + i;
  if (wid >= 6) {
    int b = wid - 6;
#pragma unroll
    for (int i = 0; i < 4; ++i) ntb[i] = 36 + b * 4 + i;
    ntb[4] = 44 + b * 2; ntb[5] = 45 + b * 2;
  }

  // ---- persistent weight fragments & biases ----
  bf16x8 w1f[6][4];
  f32x4 b1v[6];
#pragma unroll
  for (int i = 0; i < 6; ++i) {
#pragma unroll
    for (int ks = 0; ks < 4; ++ks) w1f[i][ks] = L1F[(ntb[i] * 4 + ks) * 64 + l];
    b1v[i] = *(const f32x4*)(B1 + ntb[i] * 16 + lhi * 4);
  }
  bf16x8 w2f[2][2];
  f32x4 b2v[2];
#pragma unroll
  for (int i = 0; i < 2; ++i) {
#pragma unroll
    for (int ks = 0; ks < 2; ++ks) w2f[i][ks] = L2F[((wid * 2 + i) * 2 + ks) * 64 + l];
    b2v[i] = *(const f32x4*)(B2 + wid * 32 + i * 16 + lhi * 4);
  }
  bf16x8 wgf[2];
  f32x4 bgv = (f32x4){0.f, 0.f, 0.f, 0.f};
  if (wid >= 5) {
    int t = wid - 5;
#pragma unroll
    for (int ks = 0; ks < 2; ++ks) wgf[ks] = L2F[((16 + t) * 2 + ks) * 64 + l];
    bgv = *(const f32x4*)(B2 + 256 + t * 16 + lhi * 4);
  }

  // ---- x staging mapping: thread -> (row 0..31, 8-float col group) ----
  const int r32 = tid >> 4;
  const int c8  = (tid & 15) * 8;
  const int sboff = (r32 >> 4) * 4096 + (r32 & 15) * 256 + (((tid & 15) * 16) ^ ((r32 & 7) << 4));
  const int rowbase = blockIdx.x * 1024;   // 32 iters * 32 rows

  {  // prologue: stage tile 0 into buf 0
    const float* xp = x + (size_t)(rowbase + r32) * 128 + c8;
    float4 a = *(const float4*)xp, b = *(const float4*)(xp + 4);
    u32x4 p; p[0] = cvtpk(a.x, a.y); p[1] = cvtpk(a.z, a.w);
    p[2] = cvtpk(b.x, b.y); p[3] = cvtpk(b.z, b.w);
    *(u32x4*)(lds + XSB + sboff) = p;
  }
  __syncthreads();

  int cur = 0;
#pragma unroll 1
  for (int it = 0; it < 32; ++it) {
    const int par = it & 1;
    const bool stage = (it + 1 < 32);

    // ======== section 1: stage-issue(it+1) | layer-1 both subs ========
    float4 sa, sb;
    if (stage) {
      const float* xp = x + (size_t)(rowbase + (it + 1) * 32 + r32) * 128 + c8;
      sa = *(const float4*)xp; sb = *(const float4*)(xp + 4);
    }

#pragma unroll
    for (int m = 0; m < 2; ++m) {
      bf16x8 xa[4];
#pragma unroll
      for (int ks = 0; ks < 4; ++ks)
        xa[ks] = *(const bf16x8*)(lds + XSB + cur * 8192 + m * 4096 + l15 * 256 +
                                  ((ks * 64 + lhi * 16) ^ swz));
      f32x4 acc[6];
#pragma unroll
      for (int i = 0; i < 6; ++i) acc[i] = b1v[i];
#pragma unroll
      for (int ks = 0; ks < 4; ++ks)
#pragma unroll
        for (int i = 0; i < 6; ++i)
          acc[i] = MFMA16(w1f[i][ks], xa[ks], acc[i]);
#pragma unroll
      for (int i = 0; i < 6; ++i) {
        u32x2 p;
        p[0] = cvtpk(fmaxf(acc[i][0], 0.f), fmaxf(acc[i][1], 0.f));
        p[1] = cvtpk(fmaxf(acc[i][2], 0.f), fmaxf(acc[i][3], 0.f));
        *(u32x2*)(lds + H1B + m * 24576 + l15 * 1536 + ((ntb[i] * 32 + lhi * 8) ^ swz)) = p;
      }
    }
    __syncthreads();  // bar1: h1 ready for both subs

    // ======== section 2: L2 | gates (w5-7) | combine(it-1) (w0-3) | stage-write ========
#pragma unroll
    for (int m = 0; m < 2; ++m) {
      bf16x8 hb0 = *(const bf16x8*)(lds + H1B + m * 24576 + l15 * 1536 + ((wid * 128 + lhi * 16) ^ swz));
      bf16x8 hb1 = *(const bf16x8*)(lds + H1B + m * 24576 + l15 * 1536 + ((wid * 128 + 64 + lhi * 16) ^ swz));
      f32x4 a2[2] = {b2v[0], b2v[1]};
#pragma unroll
      for (int i = 0; i < 2; ++i) {
        a2[i] = MFMA16(w2f[i][0], hb0, a2[i]);
        a2[i] = MFMA16(w2f[i][1], hb1, a2[i]);
        u32x2 p;
        p[0] = cvtpk(fmaxf(a2[i][0], 0.f), fmaxf(a2[i][1], 0.f));
        p[1] = cvtpk(fmaxf(a2[i][2], 0.f), fmaxf(a2[i][3], 0.f));
        // EO bf16: lin = wid*64 + i*32 + lhi*8; swz XOR touches bits 4-6 only
        *(u32x2*)(lds + EOB + par * 16384 + m * 8192 + l15 * 512 +
                  ((wid * 64 + i * 32 + lhi * 8) ^ swz)) = p;
      }

      if (wid >= 5) {  // gate for task wid-5, in-register softmax
        int t = wid - 5;
        bf16x8 gb0 = *(const bf16x8*)(lds + H1B + m * 24576 + l15 * 1536 + ((1024 + t * 128 + lhi * 16) ^ swz));
        bf16x8 gb1 = *(const bf16x8*)(lds + H1B + m * 24576 + l15 * 1536 + ((1024 + t * 128 + 64 + lhi * 16) ^ swz));
        f32x4 ag = bgv;
        ag = MFMA16(wgf[0], gb0, ag);
        ag = MFMA16(wgf[1], gb1, ag);
        float s0 = ag[0], s1 = ag[1], s2 = ag[2], s3 = ag[3];
        float o0 = __shfl_xor(s0, 16), o1 = __shfl_xor(s1, 16);
        float o2 = __shfl_xor(s2, 16), o3 = __shfl_xor(s3, 16);
        float mx = fmaxf(fmaxf(fmaxf(s0, s1), fmaxf(s2, s3)),
                         fmaxf(fmaxf(o0, o1), fmaxf(o2, o3)));
        float q0 = __expf(s0 - mx), q1 = __expf(s1 - mx), q2 = __expf(s2 - mx), q3 = __expf(s3 - mx);
        float ps = q0 + q1 + q2 + q3;
        float inv = 1.f / (ps + __shfl_xor(ps, 16));
        if (lhi < 2)
          *(f32x4*)(lds + SGB + par * 3584 + m * 1792 + l15 * 112 + t * 32 + lhi * 16) =
              (f32x4){q0 * inv, q1 * inv, q2 * inv, q3 * inv};
      }
    }

    if (it > 0 && wid < 4) {  // combine + store for tile it-1 (parity^1 buffers)
      const int m = wid >> 1;              // subtile
      const int c = lhi + 4 * (wid & 1);   // 4-col chunk 0..7
      const unsigned char* sgp = lds + SGB + (par ^ 1) * 3584 + m * 1792 + l15 * 112;
      f32x4 g0a = *(const f32x4*)(sgp +  0), g0b = *(const f32x4*)(sgp + 16);
      f32x4 g1a = *(const f32x4*)(sgp + 32), g1b = *(const f32x4*)(sgp + 48);
      f32x4 g2a = *(const f32x4*)(sgp + 64), g2b = *(const f32x4*)(sgp + 80);
      f32x4 v0 = (f32x4){0.f,0.f,0.f,0.f}, v1 = v0, v2 = v0;
#pragma unroll
      for (int e = 0; e < 8; ++e) {
        u32x2 q = *(const u32x2*)(lds + EOB + (par ^ 1) * 16384 + m * 8192 + l15 * 512 +
                                  ((e * 64 + c * 8) ^ swz));
        f32x4 eo;
        eo[0] = __uint_as_float(q[0] << 16);
        eo[1] = __uint_as_float(q[0] & 0xffff0000u);
        eo[2] = __uint_as_float(q[1] << 16);
        eo[3] = __uint_as_float(q[1] & 0xffff0000u);
        float ga = (e < 4) ? g0a[e & 3] : g0b[e & 3];
        float gb = (e < 4) ? g1a[e & 3] : g1b[e & 3];
        float gc = (e < 4) ? g2a[e & 3] : g2b[e & 3];
        v0 += ga * eo; v1 += gb * eo; v2 += gc * eo;
      }
      size_t rowg = (size_t)(rowbase + (it - 1) * 32 + m * 16 + l15) * 32 + c * 4;
      *(float4*)(out + rowg)                    = (float4){v0[0], v0[1], v0[2], v0[3]};
      *(float4*)(out + OUT_TASK_F32 + rowg)     = (float4){v1[0], v1[1], v1[2], v1[3]};
      *(float4*)(out + 2 * OUT_TASK_F32 + rowg) = (float4){v2[0], v2[1], v2[2], v2[3]};
    }

    if (stage) {
      u32x4 p; p[0] = cvtpk(sa.x, sa.y); p[1] = cvtpk(sa.z, sa.w);
      p[2] = cvtpk(sb.x, sb.y); p[3] = cvtpk(sb.z, sb.w);
      *(u32x4*)(lds + XSB + (cur ^ 1) * 8192 + sboff) = p;
    }
    __syncthreads();  // bar2: EO/SG(par) ready, x(it+1) staged
    cur ^= 1;
  }

  // ---- epilogue: combine for the last tile (it=31 -> parity 1) ----
  if (wid < 4) {
    const int m = wid >> 1;
    const int c = lhi + 4 * (wid & 1);
    const unsigned char* sgp = lds + SGB + 1 * 3584 + m * 1792 + l15 * 112;
    f32x4 g0a = *(const f32x4*)(sgp +  0), g0b = *(const f32x4*)(sgp + 16);
    f32x4 g1a = *(const f32x4*)(sgp + 32), g1b = *(const f32x4*)(sgp + 48);
    f32x4 g2a = *(const f32x4*)(sgp + 64), g2b = *(const f32x4*)(sgp + 80);
    f32x4 v0 = (f32x4){0.f,0.f,0.f,0.f}, v1 = v0, v2 = v0;
#pragma unroll
    for (int e = 0; e < 8; ++e) {
      u32x2 q = *(const u32x2*)(lds + EOB + 1 * 16384 + m * 8192 + l15 * 512 +
                                ((e * 64 + c * 8) ^ swz));
      f32x4 eo;
      eo[0] = __uint_as_float(q[0] << 16);
      eo[1] = __uint_as_float(q[0] & 0xffff0000u);
      eo[2] = __uint_as_float(q[1] << 16);
      eo[3] = __uint_as_float(q[1] & 0xffff0000u);
      float ga = (e < 4) ? g0a[e & 3] : g0b[e & 3];
      float gb = (e < 4) ? g1a[e & 3] : g1b[e & 3];
      float gc = (e < 4) ? g2a[e & 3] : g2b[e & 3];
      v0 += ga * eo; v1 += gb * eo; v2 += gc * eo;
    }
    size_t rowg = (size_t)(rowbase + 31 * 32 + m * 16 + l15) * 32 + c * 4;
    *(float4*)(out + rowg)                    = (float4){v0[0], v0[1], v0[2], v0[3]};
    *(float4*)(out + OUT_TASK_F32 + rowg)     = (float4){v1[0], v1[1], v1[2], v1[3]};
    *(float4*)(out + 2 * OUT_TASK_F32 + rowg) = (float4){v2[0], v2[1], v2[2], v2[3]};
  }
}

extern "C" void kernel_launch(void* const* d_in, const int* in_sizes, int n_in,
                              void* d_out, int out_size, void* d_ws, size_t ws_size,
                              hipStream_t stream) {
  const float* x   = (const float*)d_in[0];
  const float* We1 = (const float*)d_in[1];
  const float* be1 = (const float*)d_in[2];
  const float* We2 = (const float*)d_in[3];
  const float* be2 = (const float*)d_in[4];
  const float* Wg1 = (const float*)d_in[5];
  const float* bg1 = (const float*)d_in[6];
  const float* Wg2 = (const float*)d_in[7];
  const float* bg2 = (const float*)d_in[8];
  unsigned char* ws = (unsigned char*)d_ws;
  float* out = (float*)d_out;

  pack_kernel<<<465, 256, 0, stream>>>(We1, be1, We2, be2, Wg1, bg1, Wg2, bg2, ws);
  mmoe_kernel<<<256, 512, 0, stream>>>(x, ws, out);
}

// Round 19
// 87.456 us; speedup vs baseline: 3.3299x; 1.0159x over previous
//
#include <hip/hip_runtime.h>

// ---------------- problem constants ----------------
#define BROWS 262144
#define OUT_TASK_F32 8388608   // 262144*32 f32 per task; d_out = [T=3][B][32] f32

// ws layout (bytes)
#define WS_L1F 0          // 48 ntile * 4 kstep * 64 lane * 8 bf16 = 196608 B
#define WS_L2F 196608     // 19 ntile * 2 kstep * 64 lane * 8 bf16 = 38912 B
#define WS_B1  235520     // 768 f32 (layer-1 bias, padded cols -> 0)
#define WS_B2  238592     // 304 f32 (layer-2 bias: 8*32 expert + 3*16 gate-pad)

// LDS regions (bytes)  -- M=32 per iter as 2 subtiles of 16 rows
// EO/SG double-buffered on ITER PARITY (combine runs in sec2 on parity^1).
// EO packed BF16: [2 par][2 sub][16 rows][8e*32o bf16 = 512 B], XOR-swz.
#define H1B 0             // h1 bf16 [2 sub][16][768], XOR-swz                49152
#define EOB 49152         // expert out bf16 [2 par][2 sub][16][512B]         32768
#define SGB 81920         // gate probs f32 [2 par][2 sub][16][112B row]       7168
#define XSB 89088         // x bf16 [2 buf][2 sub][16][128]                   16384
#define LDS_TOTAL 105472

typedef __attribute__((ext_vector_type(8))) short bf16x8;
typedef __attribute__((ext_vector_type(4))) float f32x4;
typedef __attribute__((ext_vector_type(2))) unsigned int u32x2;
typedef __attribute__((ext_vector_type(4))) unsigned int u32x4;

#define MFMA16(a, b, c) __builtin_amdgcn_mfma_f32_16x16x32_bf16((a), (b), (c), 0, 0, 0)

__device__ __forceinline__ unsigned short f2bf(float f) {
  unsigned int u = __float_as_uint(f);
  return (unsigned short)((u + 0x7FFFu + ((u >> 16) & 1u)) >> 16);  // RNE
}
__device__ __forceinline__ unsigned int cvtpk(float lo, float hi) {
  unsigned int r;
  asm("v_cvt_pk_bf16_f32 %0, %1, %2" : "=v"(r) : "v"(lo), "v"(hi));
  return r;
}

// ---------------- weight packing (unchanged; verified) ----------------
__global__ void pack_kernel(const float* __restrict__ We1, const float* __restrict__ be1,
                            const float* __restrict__ We2, const float* __restrict__ be2,
                            const float* __restrict__ Wg1, const float* __restrict__ bg1,
                            const float* __restrict__ Wg2, const float* __restrict__ bg2,
                            unsigned char* __restrict__ ws) {
  int idx = blockIdx.x * blockDim.x + threadIdx.x;
  unsigned short* L1F = (unsigned short*)(ws + WS_L1F);
  unsigned short* L2F = (unsigned short*)(ws + WS_L2F);
  float* B1 = (float*)(ws + WS_B1);
  float* B2 = (float*)(ws + WS_B2);
  if (idx < 98304) {
    int j = idx & 7, lane = (idx >> 3) & 63, ks = (idx >> 9) & 3, nt = idx >> 11;
    int k = ks * 32 + ((lane >> 4) << 3) + j;
    int n = nt * 16 + (lane & 15);
    float v = 0.f;
    if (n < 512)      v = We1[((n >> 6) * 128 + k) * 64 + (n & 63)];
    else if (n < 704) v = Wg1[(((n - 512) >> 6) * 128 + k) * 64 + ((n - 512) & 63)];
    L1F[idx] = f2bf(v);
  } else if (idx < 98304 + 19456) {
    int i2 = idx - 98304;
    int j = i2 & 7, lane = (i2 >> 3) & 63, ks = (i2 >> 9) & 1, nt = i2 >> 10;
    int k = ks * 32 + ((lane >> 4) << 3) + j;
    int n = nt * 16 + (lane & 15);
    float v = 0.f;
    if (n < 256) v = We2[((n >> 5) * 64 + k) * 32 + (n & 31)];
    else { int g = n - 256, t = g >> 4, eo = g & 15; if (eo < 8) v = Wg2[(t * 64 + k) * 8 + eo]; }
    L2F[i2] = f2bf(v);
  } else if (idx < 98304 + 19456 + 768) {
    int n = idx - (98304 + 19456);
    float v = 0.f;
    if (n < 512)      v = be1[n];
    else if (n < 704) v = bg1[n - 512];
    B1[n] = v;
  } else if (idx < 98304 + 19456 + 768 + 304) {
    int n = idx - (98304 + 19456 + 768);
    float v = 0.f;
    if (n < 256) v = be2[n];
    else { int g = n - 256, t = g >> 4, eo = g & 15; if (eo < 8) v = bg2[t * 8 + eo]; }
    B2[n] = v;
  }
}

// ---------------- fused MMoE: r18 + s_setprio around MFMA clusters (T5 probe) ----------------
// 8 waves, M=32/iter (2 subtiles), 2 barriers/iter, 256 blocks, LDS x staging.
// sec1: stage-issue x(it+1) | L1 both subs (all waves)           [setprio on MFMA]
// sec2: L2 (all) | gates (w5-7) | combine(it-1) (w0-3, par^1)    [setprio on MFMA]
//       | stage-write x(it+1).
__global__ __launch_bounds__(512, 2) void mmoe_kernel(const float* __restrict__ x,
                                                      const unsigned char* __restrict__ ws,
                                                      float* __restrict__ out) {
  __shared__ unsigned char lds[LDS_TOTAL];

  const int tid = threadIdx.x;
  const int l   = tid & 63;
  const int wid = tid >> 6;
  const int l15 = l & 15;
  const int lhi = l >> 4;
  const int swz = (l15 & 7) << 4;

  const bf16x8* L1F = (const bf16x8*)(ws + WS_L1F);
  const bf16x8* L2F = (const bf16x8*)(ws + WS_L2F);
  const float*  B1  = (const float*)(ws + WS_B1);
  const float*  B2  = (const float*)(ws + WS_B2);

  // ---- layer-1 ntile ownership: waves 0-5: 6 real tiles; waves 6,7: 4 real + 2 pad ----
  int ntb[6];
#pragma unroll
  for (int i = 0; i < 6; ++i) ntb[i] = wid * 6 + i;
  if (wid >= 6) {
    int b = wid - 6;
#pragma unroll
    for (int i = 0; i < 4; ++i) ntb[i] = 36 + b * 4 + i;
    ntb[4] = 44 + b * 2; ntb[5] = 45 + b * 2;
  }

  // ---- persistent weight fragments & biases ----
  bf16x8 w1f[6][4];
  f32x4 b1v[6];
#pragma unroll
  for (int i = 0; i < 6; ++i) {
#pragma unroll
    for (int ks = 0; ks < 4; ++ks) w1f[i][ks] = L1F[(ntb[i] * 4 + ks) * 64 + l];
    b1v[i] = *(const f32x4*)(B1 + ntb[i] * 16 + lhi * 4);
  }
  bf16x8 w2f[2][2];
  f32x4 b2v[2];
#pragma unroll
  for (int i = 0; i < 2; ++i) {
#pragma unroll
    for (int ks = 0; ks < 2; ++ks) w2f[i][ks] = L2F[((wid * 2 + i) * 2 + ks) * 64 + l];
    b2v[i] = *(const f32x4*)(B2 + wid * 32 + i * 16 + lhi * 4);
  }
  bf16x8 wgf[2];
  f32x4 bgv = (f32x4){0.f, 0.f, 0.f, 0.f};
  if (wid >= 5) {
    int t = wid - 5;
#pragma unroll
    for (int ks = 0; ks < 2; ++ks) wgf[ks] = L2F[((16 + t) * 2 + ks) * 64 + l];
    bgv = *(const f32x4*)(B2 + 256 + t * 16 + lhi * 4);
  }

  // ---- x staging mapping: thread -> (row 0..31, 8-float col group) ----
  const int r32 = tid >> 4;
  const int c8  = (tid & 15) * 8;
  const int sboff = (r32 >> 4) * 4096 + (r32 & 15) * 256 + (((tid & 15) * 16) ^ ((r32 & 7) << 4));
  const int rowbase = blockIdx.x * 1024;   // 32 iters * 32 rows

  {  // prologue: stage tile 0 into buf 0
    const float* xp = x + (size_t)(rowbase + r32) * 128 + c8;
    float4 a = *(const float4*)xp, b = *(const float4*)(xp + 4);
    u32x4 p; p[0] = cvtpk(a.x, a.y); p[1] = cvtpk(a.z, a.w);
    p[2] = cvtpk(b.x, b.y); p[3] = cvtpk(b.z, b.w);
    *(u32x4*)(lds + XSB + sboff) = p;
  }
  __syncthreads();

  int cur = 0;
#pragma unroll 1
  for (int it = 0; it < 32; ++it) {
    const int par = it & 1;
    const bool stage = (it + 1 < 32);

    // ======== section 1: stage-issue(it+1) | layer-1 both subs ========
    float4 sa, sb;
    if (stage) {
      const float* xp = x + (size_t)(rowbase + (it + 1) * 32 + r32) * 128 + c8;
      sa = *(const float4*)xp; sb = *(const float4*)(xp + 4);
    }

#pragma unroll
    for (int m = 0; m < 2; ++m) {
      bf16x8 xa[4];
#pragma unroll
      for (int ks = 0; ks < 4; ++ks)
        xa[ks] = *(const bf16x8*)(lds + XSB + cur * 8192 + m * 4096 + l15 * 256 +
                                  ((ks * 64 + lhi * 16) ^ swz));
      f32x4 acc[6];
#pragma unroll
      for (int i = 0; i < 6; ++i) acc[i] = b1v[i];
      __builtin_amdgcn_s_setprio(1);
#pragma unroll
      for (int ks = 0; ks < 4; ++ks)
#pragma unroll
        for (int i = 0; i < 6; ++i)
          acc[i] = MFMA16(w1f[i][ks], xa[ks], acc[i]);
      __builtin_amdgcn_s_setprio(0);
#pragma unroll
      for (int i = 0; i < 6; ++i) {
        u32x2 p;
        p[0] = cvtpk(fmaxf(acc[i][0], 0.f), fmaxf(acc[i][1], 0.f));
        p[1] = cvtpk(fmaxf(acc[i][2], 0.f), fmaxf(acc[i][3], 0.f));
        *(u32x2*)(lds + H1B + m * 24576 + l15 * 1536 + ((ntb[i] * 32 + lhi * 8) ^ swz)) = p;
      }
    }
    __syncthreads();  // bar1: h1 ready for both subs

    // ======== section 2: L2 | gates (w5-7) | combine(it-1) (w0-3) | stage-write ========
#pragma unroll
    for (int m = 0; m < 2; ++m) {
      bf16x8 hb0 = *(const bf16x8*)(lds + H1B + m * 24576 + l15 * 1536 + ((wid * 128 + lhi * 16) ^ swz));
      bf16x8 hb1 = *(const bf16x8*)(lds + H1B + m * 24576 + l15 * 1536 + ((wid * 128 + 64 + lhi * 16) ^ swz));
      f32x4 a2[2] = {b2v[0], b2v[1]};
      __builtin_amdgcn_s_setprio(1);
#pragma unroll
      for (int i = 0; i < 2; ++i) {
        a2[i] = MFMA16(w2f[i][0], hb0, a2[i]);
        a2[i] = MFMA16(w2f[i][1], hb1, a2[i]);
      }
      __builtin_amdgcn_s_setprio(0);
#pragma unroll
      for (int i = 0; i < 2; ++i) {
        u32x2 p;
        p[0] = cvtpk(fmaxf(a2[i][0], 0.f), fmaxf(a2[i][1], 0.f));
        p[1] = cvtpk(fmaxf(a2[i][2], 0.f), fmaxf(a2[i][3], 0.f));
        *(u32x2*)(lds + EOB + par * 16384 + m * 8192 + l15 * 512 +
                  ((wid * 64 + i * 32 + lhi * 8) ^ swz)) = p;
      }

      if (wid >= 5) {  // gate for task wid-5, in-register softmax
        int t = wid - 5;
        bf16x8 gb0 = *(const bf16x8*)(lds + H1B + m * 24576 + l15 * 1536 + ((1024 + t * 128 + lhi * 16) ^ swz));
        bf16x8 gb1 = *(const bf16x8*)(lds + H1B + m * 24576 + l15 * 1536 + ((1024 + t * 128 + 64 + lhi * 16) ^ swz));
        f32x4 ag = bgv;
        __builtin_amdgcn_s_setprio(1);
        ag = MFMA16(wgf[0], gb0, ag);
        ag = MFMA16(wgf[1], gb1, ag);
        __builtin_amdgcn_s_setprio(0);
        float s0 = ag[0], s1 = ag[1], s2 = ag[2], s3 = ag[3];
        float o0 = __shfl_xor(s0, 16), o1 = __shfl_xor(s1, 16);
        float o2 = __shfl_xor(s2, 16), o3 = __shfl_xor(s3, 16);
        float mx = fmaxf(fmaxf(fmaxf(s0, s1), fmaxf(s2, s3)),
                         fmaxf(fmaxf(o0, o1), fmaxf(o2, o3)));
        float q0 = __expf(s0 - mx), q1 = __expf(s1 - mx), q2 = __expf(s2 - mx), q3 = __expf(s3 - mx);
        float ps = q0 + q1 + q2 + q3;
        float inv = 1.f / (ps + __shfl_xor(ps, 16));
        if (lhi < 2)
          *(f32x4*)(lds + SGB + par * 3584 + m * 1792 + l15 * 112 + t * 32 + lhi * 16) =
              (f32x4){q0 * inv, q1 * inv, q2 * inv, q3 * inv};
      }
    }

    if (it > 0 && wid < 4) {  // combine + store for tile it-1 (parity^1 buffers)
      const int m = wid >> 1;              // subtile
      const int c = lhi + 4 * (wid & 1);   // 4-col chunk 0..7
      const unsigned char* sgp = lds + SGB + (par ^ 1) * 3584 + m * 1792 + l15 * 112;
      f32x4 g0a = *(const f32x4*)(sgp +  0), g0b = *(const f32x4*)(sgp + 16);
      f32x4 g1a = *(const f32x4*)(sgp + 32), g1b = *(const f32x4*)(sgp + 48);
      f32x4 g2a = *(const f32x4*)(sgp + 64), g2b = *(const f32x4*)(sgp + 80);
      f32x4 v0 = (f32x4){0.f,0.f,0.f,0.f}, v1 = v0, v2 = v0;
#pragma unroll
      for (int e = 0; e < 8; ++e) {
        u32x2 q = *(const u32x2*)(lds + EOB + (par ^ 1) * 16384 + m * 8192 + l15 * 512 +
                                  ((e * 64 + c * 8) ^ swz));
        f32x4 eo;
        eo[0] = __uint_as_float(q[0] << 16);
        eo[1] = __uint_as_float(q[0] & 0xffff0000u);
        eo[2] = __uint_as_float(q[1] << 16);
        eo[3] = __uint_as_float(q[1] & 0xffff0000u);
        float ga = (e < 4) ? g0a[e & 3] : g0b[e & 3];
        float gb = (e < 4) ? g1a[e & 3] : g1b[e & 3];
        float gc = (e < 4) ? g2a[e & 3] : g2b[e & 3];
        v0 += ga * eo; v1 += gb * eo; v2 += gc * eo;
      }
      size_t rowg = (size_t)(rowbase + (it - 1) * 32 + m * 16 + l15) * 32 + c * 4;
      *(float4*)(out + rowg)                    = (float4){v0[0], v0[1], v0[2], v0[3]};
      *(float4*)(out + OUT_TASK_F32 + rowg)     = (float4){v1[0], v1[1], v1[2], v1[3]};
      *(float4*)(out + 2 * OUT_TASK_F32 + rowg) = (float4){v2[0], v2[1], v2[2], v2[3]};
    }

    if (stage) {
      u32x4 p; p[0] = cvtpk(sa.x, sa.y); p[1] = cvtpk(sa.z, sa.w);
      p[2] = cvtpk(sb.x, sb.y); p[3] = cvtpk(sb.z, sb.w);
      *(u32x4*)(lds + XSB + (cur ^ 1) * 8192 + sboff) = p;
    }
    __syncthreads();  // bar2: EO/SG(par) ready, x(it+1) staged
    cur ^= 1;
  }

  // ---- epilogue: combine for the last tile (it=31 -> parity 1) ----
  if (wid < 4) {
    const int m = wid >> 1;
    const int c = lhi + 4 * (wid & 1);
    const unsigned char* sgp = lds + SGB + 1 * 3584 + m * 1792 + l15 * 112;
    f32x4 g0a = *(const f32x4*)(sgp +  0), g0b = *(const f32x4*)(sgp + 16);
    f32x4 g1a = *(const f32x4*)(sgp + 32), g1b = *(const f32x4*)(sgp + 48);
    f32x4 g2a = *(const f32x4*)(sgp + 64), g2b = *(const f32x4*)(sgp + 80);
    f32x4 v0 = (f32x4){0.f,0.f,0.f,0.f}, v1 = v0, v2 = v0;
#pragma unroll
    for (int e = 0; e < 8; ++e) {
      u32x2 q = *(const u32x2*)(lds + EOB + 1 * 16384 + m * 8192 + l15 * 512 +
                                ((e * 64 + c * 8) ^ swz));
      f32x4 eo;
      eo[0] = __uint_as_float(q[0] << 16);
      eo[1] = __uint_as_float(q[0] & 0xffff0000u);
      eo[2] = __uint_as_float(q[1] << 16);
      eo[3] = __uint_as_float(q[1] & 0xffff0000u);
      float ga = (e < 4) ? g0a[e & 3] : g0b[e & 3];
      float gb = (e < 4) ? g1a[e & 3] : g1b[e & 3];
      float gc = (e < 4) ? g2a[e & 3] : g2b[e & 3];
      v0 += ga * eo; v1 += gb * eo; v2 += gc * eo;
    }
    size_t rowg = (size_t)(rowbase + 31 * 32 + m * 16 + l15) * 32 + c * 4;
    *(float4*)(out + rowg)                    = (float4){v0[0], v0[1], v0[2], v0[3]};
    *(float4*)(out + OUT_TASK_F32 + rowg)     = (float4){v1[0], v1[1], v1[2], v1[3]};
    *(float4*)(out + 2 * OUT_TASK_F32 + rowg) = (float4){v2[0], v2[1], v2[2], v2[3]};
  }
}

extern "C" void kernel_launch(void* const* d_in, const int* in_sizes, int n_in,
                              void* d_out, int out_size, void* d_ws, size_t ws_size,
                              hipStream_t stream) {
  const float* x   = (const float*)d_in[0];
  const float* We1 = (const float*)d_in[1];
  const float* be1 = (const float*)d_in[2];
  const float* We2 = (const float*)d_in[3];
  const float* be2 = (const float*)d_in[4];
  const float* Wg1 = (const float*)d_in[5];
  const float* bg1 = (const float*)d_in[6];
  const float* Wg2 = (const float*)d_in[7];
  const float* bg2 = (const float*)d_in[8];
  unsigned char* ws = (unsigned char*)d_ws;
  float* out = (float*)d_out;

  pack_kernel<<<465, 256, 0, stream>>>(We1, be1, We2, be2, Wg1, bg1, Wg2, bg2, ws);
  mmoe_kernel<<<256, 512, 0, stream>>>(x, ws, out);
}